// Round 1
// baseline (1140.932 us; speedup 1.0000x reference)
//
#include <hip/hip_runtime.h>

// Problem geometry
// x: (8,96,256,256) fp32. BC = 768 images of 256x256.
// Out 0: xlo (768,128,128)  = 12,582,912 floats
// Out 1: xhi_dir (768,4,128,128) = 50,331,648 floats
// Scratch: xhi (768,256,256) staged in the out-1 region; y0/y1 in d_ws.

#define BC 768

// ---------------------------------------------------------------------------
// K1: xlo[r,c] = sum_{i,j<5} h[i]h[j] x[(2r+i-2)%256, (2c+j-2)%256]
// ---------------------------------------------------------------------------
__global__ __launch_bounds__(256) void k1_lowpass(
    const float* __restrict__ x, const float* __restrict__ h,
    float* __restrict__ xlo)
{
    __shared__ float hh[25];
    int t = threadIdx.x;
    if (t < 25) hh[t] = h[t / 5] * h[t % 5];
    __syncthreads();

    int tid = blockIdx.x * 256 + t;
    int c  = tid & 127;
    int r  = (tid >> 7) & 127;
    int bc = tid >> 14;
    const float* xb = x + (size_t)bc * 65536;

    float acc = 0.f;
    #pragma unroll
    for (int i = 0; i < 5; ++i) {
        int row = (2 * r + i - 2 + 256) & 255;
        const float* xr = xb + row * 256;
        #pragma unroll
        for (int j = 0; j < 5; ++j) {
            int col = (2 * c + j - 2 + 256) & 255;
            acc += hh[i * 5 + j] * xr[col];
        }
    }
    xlo[(size_t)bc * 16384 + r * 128 + c] = acc;
}

// ---------------------------------------------------------------------------
// K2: xhi[h,w] = x[h,w] - sum_{i,j} g[i]g[j] up[(h+i-3)%256, (w+j-3)%256]
// up is zero-stuffed xlo => polyphase taps per parity.
// ---------------------------------------------------------------------------
__global__ __launch_bounds__(256) void k2_highpass(
    const float* __restrict__ x, const float* __restrict__ g,
    const float* __restrict__ xlo, float* __restrict__ xhi)
{
    __shared__ float gs[7];
    int t = threadIdx.x;
    if (t < 7) gs[t] = g[t];
    __syncthreads();

    int tid = blockIdx.x * 256 + t;
    int w  = tid & 255;
    int h  = (tid >> 8) & 255;
    int bc = tid >> 16;
    const float* lob = xlo + (size_t)bc * 16384;

    // row taps (up-row must be even)
    int r = h >> 1;
    int ri[4] = { (r - 1 + 128) & 127, r, (r + 1) & 127, (r + 2) & 127 };
    float rw[4];
    if ((h & 1) == 0) { rw[0] = gs[1]; rw[1] = gs[3]; rw[2] = gs[5]; rw[3] = 0.f; }
    else              { rw[0] = gs[0]; rw[1] = gs[2]; rw[2] = gs[4]; rw[3] = gs[6]; }

    int c = w >> 1;
    int ci[4] = { (c - 1 + 128) & 127, c, (c + 1) & 127, (c + 2) & 127 };
    float cw[4];
    if ((w & 1) == 0) { cw[0] = gs[1]; cw[1] = gs[3]; cw[2] = gs[5]; cw[3] = 0.f; }
    else              { cw[0] = gs[0]; cw[1] = gs[2]; cw[2] = gs[4]; cw[3] = gs[6]; }

    float acc = 0.f;
    #pragma unroll
    for (int a = 0; a < 4; ++a) {
        const float* lr = lob + ri[a] * 128;
        float s = 0.f;
        #pragma unroll
        for (int b = 0; b < 4; ++b) s += cw[b] * lr[ci[b]];
        acc += rw[a] * s;
    }

    size_t idx = (size_t)bc * 65536 + h * 256 + w;
    xhi[idx] = x[idx] - acc;
}

// ---------------------------------------------------------------------------
// K3: y{0,1}[r,w] = sum_{i,j} f{0,1}[i,j] xhi[(2r+i-3)%256, (w+2r+j-3)%256]
// (7x7 conv fused with quincunx row-downsample)
// ---------------------------------------------------------------------------
__global__ __launch_bounds__(256) void k3_dirfilt(
    const float* __restrict__ xhi, const float* __restrict__ f0,
    const float* __restrict__ f1, float* __restrict__ y0,
    float* __restrict__ y1)
{
    __shared__ float F0[49], F1[49];
    int t = threadIdx.x;
    if (t < 49) F0[t] = f0[t];
    else if (t < 98) F1[t - 49] = f1[t - 49];
    __syncthreads();

    int tid = blockIdx.x * 256 + t;
    int w  = tid & 255;
    int r  = (tid >> 8) & 127;
    int bc = tid >> 15;
    const float* xb = xhi + (size_t)bc * 65536;

    float a0 = 0.f, a1 = 0.f;
    #pragma unroll
    for (int i = 0; i < 7; ++i) {
        int row = (2 * r + i - 3 + 256) & 255;
        const float* xr = xb + row * 256;
        #pragma unroll
        for (int j = 0; j < 7; ++j) {
            int col = (w + 2 * r + j - 3 + 256) & 255;
            float v = xr[col];
            a0 += F0[i * 7 + j] * v;
            a1 += F1[i * 7 + j] * v;
        }
    }
    size_t o = (size_t)bc * 32768 + r * 256 + w;
    y0[o] = a0;
    y1[o] = a1;
}

// ---------------------------------------------------------------------------
// K4: out[d, hh, cc] = sum_{i,j} fT[i,j] y[(hh+2cc+i-3)%128, (2cc+j-3)%256]
// fT = f0.T / f1.T, i.e. fT[i][j] = f[j][i]. LDS-tiled to fix the stride-514
// gather. Tile: 32x32 outputs, y region 100 rows x 70 cols (padded to 80).
// ---------------------------------------------------------------------------
#define TH 32
#define TC 32
#define NR (TH + 2 * TC + 4)   // 100
#define NC (2 * TC + 6)        // 70
#define NCP 80                 // pad: lane stride 2*80+2=162 ≡ 2 banks (free)

__global__ __launch_bounds__(256) void k4_qdc(
    const float* __restrict__ ybuf, const float* __restrict__ f0,
    const float* __restrict__ f1, float* __restrict__ out_hi)
{
    __shared__ float tile[NR * NCP];
    __shared__ float F0[49], F1[49];
    int t = threadIdx.x;
    if (t < 49) F0[t] = f0[t];
    else if (t < 98) F1[t - 49] = f1[t - 49];

    int bx   = blockIdx.x;
    int ccb  = (bx & 3) * TC;
    int hhb  = ((bx >> 2) & 3) * TH;
    int yidx = (bx >> 4) & 1;
    int bc   = bx >> 5;
    const float* yb = ybuf + ((size_t)yidx * BC + bc) * 32768;

    int r0 = (hhb + 2 * ccb - 3 + 128) & 127;
    int c0 = (2 * ccb - 3 + 256) & 255;

    for (int idx = t; idx < NR * NC; idx += 256) {
        int rr = idx / NC;
        int cc = idx - rr * NC;
        int gr = (r0 + rr) & 127;
        int gc = (c0 + cc) & 255;
        tile[rr * NCP + cc] = yb[gr * 256 + gc];
    }
    __syncthreads();

    int lc = t & 31;        // delta cc
    int lh = t >> 5;        // 0..7
    int cc = ccb + lc;
    int cbase = 2 * lc;

    #pragma unroll
    for (int k = 0; k < 4; ++k) {
        int dhh = lh + 8 * k;
        int hh  = hhb + dhh;
        int rbase = dhh + 2 * lc;
        float s0 = 0.f, s1 = 0.f;
        #pragma unroll
        for (int i = 0; i < 7; ++i) {
            const float* tr = &tile[(rbase + i) * NCP + cbase];
            #pragma unroll
            for (int j = 0; j < 7; ++j) {
                float v = tr[j];
                s0 += F0[j * 7 + i] * v;   // f0.T
                s1 += F1[j * 7 + i] * v;   // f1.T
            }
        }
        size_t o = (size_t)bc * 65536 + (size_t)(2 * yidx) * 16384
                 + (size_t)hh * 128 + cc;
        out_hi[o]         = s0;
        out_hi[o + 16384] = s1;
    }
}

// ---------------------------------------------------------------------------
extern "C" void kernel_launch(void* const* d_in, const int* in_sizes, int n_in,
                              void* d_out, int out_size, void* d_ws, size_t ws_size,
                              hipStream_t stream)
{
    const float* x  = (const float*)d_in[0];
    const float* h  = (const float*)d_in[1];
    const float* g  = (const float*)d_in[2];
    const float* f0 = (const float*)d_in[3];
    const float* f1 = (const float*)d_in[4];

    float* out  = (float*)d_out;
    float* xlo  = out;                 // 768*16384 floats
    float* hireg = out + 12582912;     // 768*65536 floats: xhi scratch, then final subbands
    float* ybuf = (float*)d_ws;        // y0 then y1, each 768*32768 floats (201 MB total)

    k1_lowpass<<<49152, 256, 0, stream>>>(x, h, xlo);
    k2_highpass<<<196608, 256, 0, stream>>>(x, g, xlo, hireg);
    k3_dirfilt<<<98304, 256, 0, stream>>>(hireg, f0, f1, ybuf, ybuf + 25165824);
    k4_qdc<<<24576, 256, 0, stream>>>(ybuf, f0, f1, hireg);
}